// Round 11
// baseline (94.185 us; speedup 1.0000x reference)
//
#include <hip/hip_runtime.h>

#define TLEN 1000000
#define YS 64
#define XS 50000
#define CHUNK 16
#define WARM 8
#define SPAN (CHUNK + WARM)                    // 24 steps/wave (6 macro x 4)
#define NCHUNK (TLEN / CHUNK)                  // 62500
#define RPW 16                                 // chunks per wave (MFMA N dim)
#define NW ((NCHUNK + RPW - 1) / RPW)          // 3907
#define WPB 4
#define NBLK ((NW + WPB - 1) / WPB)            // 977
#define BSCALE ((float)XS)                     // keeps bf16 e near 1

typedef float f32x4 __attribute__((ext_vector_type(4)));
typedef short bf16x8 __attribute__((ext_vector_type(8)));
typedef unsigned int u32x4 __attribute__((ext_vector_type(4)));

__device__ __forceinline__ unsigned cvtpk(float lo, float hi) {
  unsigned r;
  asm("v_cvt_pk_bf16_f32 %0, %1, %2" : "=v"(r) : "v"(lo), "v"(hi));
  return r;
}
__device__ __forceinline__ unsigned short f2bf_rne(float f) {
  unsigned u = __float_as_uint(f);
  unsigned r = (u + 0x7FFFu + ((u >> 16) & 1u)) >> 16;
  return (unsigned short)r;
}
__device__ __forceinline__ float bfu_lo(unsigned d) { return __uint_as_float(d << 16); }
__device__ __forceinline__ float bfu_hi(unsigned d) { return __uint_as_float(d & 0xffff0000u); }
__device__ __forceinline__ int clamp01(int t) {
  t = t < 0 ? 0 : t;
  return t > (TLEN - 1) ? (TLEN - 1) : t;
}

union bfu { u32x4 u; bf16x8 b; };

// Register-resident rho-relabeled MFMA recurrence (R8-proven numerics).
// R11: no LDS at all; direct 4x dwordx4 stores (pattern proven irrelevant at
// >=256B granularity, R8 vs R10); TLP doubled to ~3.8 waves/SIMD (3907 waves,
// LB(256,4), VGPR-bound only); e-prefetch ring deepened to 4 steps, x to 8.
template <bool USE_BT>
__global__ __launch_bounds__(256, 4) void hmm_fwd(
    const int* __restrict__ x, const float* __restrict__ A,
    const float* __restrict__ pi, const float* __restrict__ b,
    const unsigned* __restrict__ bpk, float* __restrict__ out)
{
  const int wv = blockIdx.x * WPB + (threadIdx.x >> 6);
  const int lane = threadIdx.x & 63;
  if (wv >= NW) return;
  const int g = lane >> 4, c15 = lane & 15;

  // static A-operand fragments: Af[nt][h][j] = T[sin][sout], bf16
  bf16x8 Af[4][2];
#pragma unroll
  for (int nt = 0; nt < 4; nt++) {
    int sout = 32 * (nt >> 1) + 8 * (c15 >> 2) + 4 * (nt & 1) + (c15 & 3);
#pragma unroll
    for (int h = 0; h < 2; h++) {
      bf16x8 v;
#pragma unroll
      for (int j = 0; j < 8; j++) {
        int sin = 32 * h + 8 * g + j;
        v[j] = (short)f2bf_rne(A[sin * YS + sout]);
      }
      Af[nt][h] = v;
    }
  }

  const int tj0 = (wv * RPW + c15) * CHUNK - WARM;
  const bool isw0 = (wv == 0);

  // carry B-frags: uniform start (warm-up forgets it; renormalized every step)
  u32x4 cb0, cb1;
  { unsigned one2 = 0x3f803f80u; cb0 = (u32x4){one2, one2, one2, one2}; cb1 = cb0; }

  // packed-e loader: L0 = states (8g..8g+7), L1 = states (32+8g..32+8g+7)
  auto eload = [&](int xt, u32x4& L0, u32x4& L1) {
    if (USE_BT) {
      const u32x4* p = (const u32x4*)(bpk + (size_t)(unsigned)xt * 32);
      L0 = p[g];
      L1 = p[4 + g];
    } else {
      unsigned t0[4], t1[4];
#pragma unroll
      for (int d = 0; d < 4; d++) {
        int s = 8 * g + 2 * d;
        t0[d] = cvtpk(b[(size_t)s * XS + xt] * BSCALE,
                      b[(size_t)(s + 1) * XS + xt] * BSCALE);
        int s2 = 32 + 8 * g + 2 * d;
        t1[d] = cvtpk(b[(size_t)s2 * XS + xt] * BSCALE,
                      b[(size_t)(s2 + 1) * XS + xt] * BSCALE);
      }
      L0 = (u32x4){t0[0], t0[1], t0[2], t0[3]};
      L1 = (u32x4){t1[0], t1[1], t1[2], t1[3]};
    }
  };

  // prefetch rings: e for steps 0..3 (4-deep); x values for steps 4..7
  u32x4 eL0[4], eL1[4];
  int xv[4];
#pragma unroll
  for (int u = 0; u < 4; u++) {
    eload(x[clamp01(tj0 + u)], eL0[u], eL1[u]);
    xv[u] = x[clamp01(tj0 + 4 + u)];
  }

  int trow = tj0;
  float* pout = out + (long)tj0 * YS + 8 * g;
  const f32x4 z4 = {0.f, 0.f, 0.f, 0.f};

  auto stepf = [&](int sabs, int u) {
    bfu ub0, ub1; ub0.u = cb0; ub1.u = cb1;
    bf16x8 bb0 = ub0.b, bb1 = ub1.b;

    f32x4 D0 = __builtin_amdgcn_mfma_f32_16x16x32_bf16(Af[0][0], bb0, z4, 0, 0, 0);
    f32x4 D1 = __builtin_amdgcn_mfma_f32_16x16x32_bf16(Af[1][0], bb0, z4, 0, 0, 0);
    f32x4 D2 = __builtin_amdgcn_mfma_f32_16x16x32_bf16(Af[2][0], bb0, z4, 0, 0, 0);
    f32x4 D3 = __builtin_amdgcn_mfma_f32_16x16x32_bf16(Af[3][0], bb0, z4, 0, 0, 0);
    D0 = __builtin_amdgcn_mfma_f32_16x16x32_bf16(Af[0][1], bb1, D0, 0, 0, 0);
    D1 = __builtin_amdgcn_mfma_f32_16x16x32_bf16(Af[1][1], bb1, D1, 0, 0, 0);
    D2 = __builtin_amdgcn_mfma_f32_16x16x32_bf16(Af[2][1], bb1, D2, 0, 0, 0);
    D3 = __builtin_amdgcn_mfma_f32_16x16x32_bf16(Af[3][1], bb1, D3, 0, 0, 0);

    // emission fold: D[nt][j] *= e[state(nt,g,j)]
    u32x4 L0 = eL0[u], L1 = eL1[u];
    D0[0] *= bfu_lo(L0[0]); D0[1] *= bfu_hi(L0[0]); D0[2] *= bfu_lo(L0[1]); D0[3] *= bfu_hi(L0[1]);
    D1[0] *= bfu_lo(L0[2]); D1[1] *= bfu_hi(L0[2]); D1[2] *= bfu_lo(L0[3]); D1[3] *= bfu_hi(L0[3]);
    D2[0] *= bfu_lo(L1[0]); D2[1] *= bfu_hi(L1[0]); D2[2] *= bfu_lo(L1[1]); D2[3] *= bfu_hi(L1[1]);
    D3[0] *= bfu_lo(L1[2]); D3[1] *= bfu_hi(L1[2]); D3[2] *= bfu_lo(L1[3]); D3[3] *= bfu_hi(L1[3]);

    // chunk-0 exact init injection at its t=0 (one step, wave 0, chunk col 0)
    if (isw0 && sabs == WARM && c15 == 0) {
      int x0v = x[0];
#pragma unroll
      for (int nt = 0; nt < 4; nt++) {
#pragma unroll
        for (int j = 0; j < 4; j++) {
          int s = 32 * (nt >> 1) + 8 * g + 4 * (nt & 1) + j;
          float ov = pi[s] * b[(size_t)s * XS + x0v] * BSCALE;
          if (nt == 0) D0[j] = ov;
          else if (nt == 1) D1[j] = ov;
          else if (nt == 2) D2[j] = ov;
          else D3[j] = ov;
        }
      }
    }

    // exact per-step renormalization (chunk-uniform scale; kills all drift)
    f32x4 vs = (D0 + D1) + (D2 + D3);
    float ssum = (vs.x + vs.y) + (vs.z + vs.w);
    ssum += __shfl_xor(ssum, 16);
    ssum += __shfl_xor(ssum, 32);
    float r0 = __builtin_amdgcn_rcpf(ssum);
    float rs = r0 * fmaf(-ssum, r0, 2.0f);
    f32x4 N0 = D0 * rs, N1 = D1 * rs, N2 = D2 * rs, N3 = D3 * rs;

    // carry pack (critical path): D/N regs are exactly the next B-frag states
    cb0 = (u32x4){cvtpk(N0[0], N0[1]), cvtpk(N0[2], N0[3]),
                  cvtpk(N1[0], N1[1]), cvtpk(N1[2], N1[3])};
    cb1 = (u32x4){cvtpk(N2[0], N2[1]), cvtpk(N2[2], N2[3]),
                  cvtpk(N3[0], N3[1]), cvtpk(N3[2], N3[3])};

    // off-chain: direct store of the normalized row
    if (sabs >= WARM && trow < TLEN) {
      *(f32x4*)(pout + 0)  = N0;   // states 8g+0..3
      *(f32x4*)(pout + 4)  = N1;   // states 8g+4..7
      *(f32x4*)(pout + 32) = N2;   // states 32+8g+0..3
      *(f32x4*)(pout + 36) = N3;   // states 32+8g+4..7
    }
    trow += 1;
    pout += YS;

    // refill rings: e for step sabs+4, x for step sabs+8
    eload(xv[u], eL0[u], eL1[u]);
    xv[u] = x[clamp01(tj0 + sabs + 8)];
  };

  for (int s = 0; s < SPAN; s += 4) {
    stepf(s + 0, 0);
    stepf(s + 1, 1);
    stepf(s + 2, 2);
    stepf(s + 3, 3);
  }
}

// pack b (YS x XS f32) -> bpk[x][d] = bf16 pair (state 2d, state 2d+1), pre-scaled
__global__ __launch_bounds__(256) void pack_b(
    const float* __restrict__ b, unsigned* __restrict__ bpk)
{
  __shared__ float tileb[64][65];
  int x0 = blockIdx.x << 6;
  int lane = threadIdx.x & 63;
  int w = threadIdx.x >> 6;
  int xg = x0 + lane;
#pragma unroll
  for (int yy = 0; yy < 64; yy += 4) {
    int y = yy + w;
    tileb[y][lane] = (xg < XS) ? b[(size_t)y * XS + xg] * BSCALE : 0.f;
  }
  __syncthreads();
  int d = threadIdx.x & 31;           // dword slot = state pair (2d, 2d+1)
  int xo = threadIdx.x >> 5;          // 0..7
#pragma unroll
  for (int pass = 0; pass < 8; pass++) {
    int xl = pass * 8 + xo;
    int xcur = x0 + xl;
    if (xcur < XS)
      bpk[(size_t)xcur * 32 + d] = cvtpk(tileb[2 * d][xl], tileb[2 * d + 1][xl]);
  }
}

extern "C" void kernel_launch(void* const* d_in, const int* in_sizes, int n_in,
                              void* d_out, int out_size, void* d_ws, size_t ws_size,
                              hipStream_t stream)
{
  const int*   x  = (const int*)d_in[0];
  const float* A  = (const float*)d_in[1];
  const float* b  = (const float*)d_in[2];
  const float* pi = (const float*)d_in[3];
  float* out = (float*)d_out;

  const size_t bpk_bytes = (size_t)XS * 32 * sizeof(unsigned);  // 6.4 MB

  if (ws_size >= bpk_bytes) {
    unsigned* bpk = (unsigned*)d_ws;
    int tblocks = (XS + 63) / 64;
    pack_b<<<tblocks, 256, 0, stream>>>(b, bpk);
    hmm_fwd<true><<<NBLK, 256, 0, stream>>>(x, A, pi, b, bpk, out);
  } else {
    hmm_fwd<false><<<NBLK, 256, 0, stream>>>(x, A, pi, b, nullptr, out);
  }
}

// Round 12
// 75.916 us; speedup vs baseline: 1.2406x; 1.2406x over previous
//
#include <hip/hip_runtime.h>

#define TLEN 1000000
#define YS 64
#define XS 50000
#define CHUNK 32
#define WARM 8
#define SPAN (CHUNK + WARM)                    // 40 steps/wave
#define NWIN (CHUNK / 4)                       // 8 flush windows
#define NCHUNK (TLEN / CHUNK)                  // 31250
#define RPW 16                                 // chunks per wave (MFMA N dim)
#define NW ((NCHUNK + RPW - 1) / RPW)          // 1954
#define WPB 4
#define NBLK ((NW + WPB - 1) / WPB)            // 489
#define BSCALE ((float)XS)                     // keeps bf16 e near 1

typedef float f32x4 __attribute__((ext_vector_type(4)));
typedef short bf16x8 __attribute__((ext_vector_type(8)));
typedef unsigned int u32x4 __attribute__((ext_vector_type(4)));

__device__ __forceinline__ unsigned cvtpk(float lo, float hi) {
  unsigned r;
  asm("v_cvt_pk_bf16_f32 %0, %1, %2" : "=v"(r) : "v"(lo), "v"(hi));
  return r;
}
__device__ __forceinline__ unsigned short f2bf_rne(float f) {
  unsigned u = __float_as_uint(f);
  unsigned r = (u + 0x7FFFu + ((u >> 16) & 1u)) >> 16;
  return (unsigned short)r;
}
__device__ __forceinline__ float bfu_lo(unsigned d) { return __uint_as_float(d << 16); }
__device__ __forceinline__ float bfu_hi(unsigned d) { return __uint_as_float(d & 0xffff0000u); }
__device__ __forceinline__ int clamp01(int t) {
  t = t < 0 ? 0 : t;
  return t > (TLEN - 1) ? (TLEN - 1) : t;
}

union bfu { u32x4 u; bf16x8 b; };

// Register-resident rho-relabeled MFMA recurrence (R8-proven numerics) +
// fenced LDS-staged output (R10-proven) with NON-TEMPORAL flush stores:
// the 256MB once-written output stream must not wash through L2 -- NT keeps
// L2 reserved for the 6.4MB e-table (bpk), which every step gathers from.
// CHUNK=32/WARM=8 trims warm-up overhead to 1.25x (WARM=8 validated R11).
template <bool USE_BT>
__global__ __launch_bounds__(256, 2) void hmm_fwd(
    const int* __restrict__ x, const float* __restrict__ A,
    const float* __restrict__ pi, const float* __restrict__ b,
    const unsigned* __restrict__ bpk, float* __restrict__ out)
{
  __shared__ __align__(16) float tile[WPB][64][64];   // 64KB: 4 steps x 16 chunks x 256B per wave
  const int wslot = threadIdx.x >> 6;
  const int wv = blockIdx.x * WPB + wslot;
  const int lane = threadIdx.x & 63;
  if (wv >= NW) return;
  const int g = lane >> 4, c15 = lane & 15;

  // static A-operand fragments: Af[nt][h][j] = T[sin][sout], bf16
  bf16x8 Af[4][2];
#pragma unroll
  for (int nt = 0; nt < 4; nt++) {
    int sout = 32 * (nt >> 1) + 8 * (c15 >> 2) + 4 * (nt & 1) + (c15 & 3);
#pragma unroll
    for (int h = 0; h < 2; h++) {
      bf16x8 v;
#pragma unroll
      for (int j = 0; j < 8; j++) {
        int sin = 32 * h + 8 * g + j;
        v[j] = (short)f2bf_rne(A[sin * YS + sout]);
      }
      Af[nt][h] = v;
    }
  }

  const int tj0 = (wv * RPW + c15) * CHUNK - WARM;
  const bool isw0 = (wv == 0);

  // carry B-frags: uniform start (warm-up forgets it; renormalized every step)
  u32x4 cb0, cb1;
  { unsigned one2 = 0x3f803f80u; cb0 = (u32x4){one2, one2, one2, one2}; cb1 = cb0; }

  // packed-e loader: L0 = states (8g..8g+7), L1 = states (32+8g..32+8g+7)
  auto eload = [&](int xt, u32x4& L0, u32x4& L1) {
    if (USE_BT) {
      const u32x4* p = (const u32x4*)(bpk + (size_t)(unsigned)xt * 32);
      L0 = p[g];
      L1 = p[4 + g];
    } else {
      unsigned t0[4], t1[4];
#pragma unroll
      for (int d = 0; d < 4; d++) {
        int s = 8 * g + 2 * d;
        t0[d] = cvtpk(b[(size_t)s * XS + xt] * BSCALE,
                      b[(size_t)(s + 1) * XS + xt] * BSCALE);
        int s2 = 32 + 8 * g + 2 * d;
        t1[d] = cvtpk(b[(size_t)s2 * XS + xt] * BSCALE,
                      b[(size_t)(s2 + 1) * XS + xt] * BSCALE);
      }
      L0 = (u32x4){t0[0], t0[1], t0[2], t0[3]};
      L1 = (u32x4){t1[0], t1[1], t1[2], t1[3]};
    }
  };

  // prefetch: e for steps 0,1; x for steps 2,3 (reload distance 4)
  u32x4 e0L0, e0L1, e1L0, e1L1;
  eload(x[clamp01(tj0 + 0)], e0L0, e0L1);
  eload(x[clamp01(tj0 + 1)], e1L0, e1L1);
  int xr0 = x[clamp01(tj0 + 2)];
  int xr1 = x[clamp01(tj0 + 3)];

  const f32x4 z4 = {0.f, 0.f, 0.f, 0.f};

  auto stepf = [&](int sabs, u32x4& L0, u32x4& L1, int& xr) {
    bfu ub0, ub1; ub0.u = cb0; ub1.u = cb1;
    bf16x8 bb0 = ub0.b, bb1 = ub1.b;

    f32x4 D0 = __builtin_amdgcn_mfma_f32_16x16x32_bf16(Af[0][0], bb0, z4, 0, 0, 0);
    f32x4 D1 = __builtin_amdgcn_mfma_f32_16x16x32_bf16(Af[1][0], bb0, z4, 0, 0, 0);
    f32x4 D2 = __builtin_amdgcn_mfma_f32_16x16x32_bf16(Af[2][0], bb0, z4, 0, 0, 0);
    f32x4 D3 = __builtin_amdgcn_mfma_f32_16x16x32_bf16(Af[3][0], bb0, z4, 0, 0, 0);
    D0 = __builtin_amdgcn_mfma_f32_16x16x32_bf16(Af[0][1], bb1, D0, 0, 0, 0);
    D1 = __builtin_amdgcn_mfma_f32_16x16x32_bf16(Af[1][1], bb1, D1, 0, 0, 0);
    D2 = __builtin_amdgcn_mfma_f32_16x16x32_bf16(Af[2][1], bb1, D2, 0, 0, 0);
    D3 = __builtin_amdgcn_mfma_f32_16x16x32_bf16(Af[3][1], bb1, D3, 0, 0, 0);

    // emission fold: D[nt][j] *= e[state(nt,g,j)]
    D0[0] *= bfu_lo(L0[0]); D0[1] *= bfu_hi(L0[0]); D0[2] *= bfu_lo(L0[1]); D0[3] *= bfu_hi(L0[1]);
    D1[0] *= bfu_lo(L0[2]); D1[1] *= bfu_hi(L0[2]); D1[2] *= bfu_lo(L0[3]); D1[3] *= bfu_hi(L0[3]);
    D2[0] *= bfu_lo(L1[0]); D2[1] *= bfu_hi(L1[0]); D2[2] *= bfu_lo(L1[1]); D2[3] *= bfu_hi(L1[1]);
    D3[0] *= bfu_lo(L1[2]); D3[1] *= bfu_hi(L1[2]); D3[2] *= bfu_lo(L1[3]); D3[3] *= bfu_hi(L1[3]);

    // chunk-0 exact init injection at its t=0 (one step, wave 0, chunk col 0)
    if (isw0 && sabs == WARM && c15 == 0) {
      int x0v = x[0];
#pragma unroll
      for (int nt = 0; nt < 4; nt++) {
#pragma unroll
        for (int j = 0; j < 4; j++) {
          int s = 32 * (nt >> 1) + 8 * g + 4 * (nt & 1) + j;
          float ov = pi[s] * b[(size_t)s * XS + x0v] * BSCALE;
          if (nt == 0) D0[j] = ov;
          else if (nt == 1) D1[j] = ov;
          else if (nt == 2) D2[j] = ov;
          else D3[j] = ov;
        }
      }
    }

    // exact per-step renormalization (chunk-uniform scale; kills all drift)
    f32x4 vs = (D0 + D1) + (D2 + D3);
    float ssum = (vs.x + vs.y) + (vs.z + vs.w);
    ssum += __shfl_xor(ssum, 16);
    ssum += __shfl_xor(ssum, 32);
    float r0 = __builtin_amdgcn_rcpf(ssum);
    float rs = r0 * fmaf(-ssum, r0, 2.0f);
    f32x4 N0 = D0 * rs, N1 = D1 * rs, N2 = D2 * rs, N3 = D3 * rs;

    // carry pack (critical path): D/N regs are exactly the next B-frag states
    cb0 = (u32x4){cvtpk(N0[0], N0[1]), cvtpk(N0[2], N0[3]),
                  cvtpk(N1[0], N1[1]), cvtpk(N1[2], N1[3])};
    cb1 = (u32x4){cvtpk(N2[0], N2[1]), cvtpk(N2[2], N2[3]),
                  cvtpk(N3[0], N3[1]), cvtpk(N3[2], N3[3])};

    // off-chain: stage normalized row into the LDS out-tile (XOR swizzled)
    if (sabs >= WARM) {
      const int srel = (sabs - WARM) & 3;
      float* rowp = &tile[wslot][4 * c15 + srel][0];
      const int xk = (c15 & 7) << 2;
      *(f32x4*)&rowp[(8 * g)      ^ xk] = N0;   // states 8g+0..3
      *(f32x4*)&rowp[(8 * g + 4)  ^ xk] = N1;   // states 8g+4..7
      *(f32x4*)&rowp[(32 + 8 * g) ^ xk] = N2;   // states 32+8g+0..3
      *(f32x4*)&rowp[(36 + 8 * g) ^ xk] = N3;   // states 32+8g+4..7
    }

    // refill: e for step sabs+2, x for step sabs+4
    eload(xr, L0, L1);
    xr = x[clamp01(tj0 + sabs + 4)];
  };

  // warm-up (no staging)
  for (int s = 0; s < WARM; s += 2) {
    stepf(s + 0, e0L0, e0L1, xr0);
    stepf(s + 1, e1L0, e1L1, xr1);
  }

  // output phase: NWIN windows x 4 steps; flush 16x 1KB contiguous islands,
  // NON-TEMPORAL (write-once stream must not evict bpk from L2)
  for (int w = 0; w < NWIN; w++) {
    const int sb = WARM + 4 * w;
    stepf(sb + 0, e0L0, e0L1, xr0);
    stepf(sb + 1, e1L0, e1L1, xr1);
    stepf(sb + 2, e0L0, e0L1, xr0);
    stepf(sb + 3, e1L0, e1L1, xr1);

    __builtin_amdgcn_sched_barrier(0);
    asm volatile("" ::: "memory");   // staging writes complete before flush reads
#pragma unroll
    for (int c = 0; c < 16; c++) {
      int gc = wv * RPW + c;
      if (gc < NCHUNK) {
        f32x4 v = *(const f32x4*)&tile[wslot][4 * c + g][(c15 * 4) ^ ((c & 7) << 2)];
        __builtin_nontemporal_store(v,
            (f32x4*)(out + ((size_t)gc * CHUNK + 4 * w + g) * YS + c15 * 4));
      }
    }
    asm volatile("" ::: "memory");   // flush reads complete before next staging writes
    __builtin_amdgcn_sched_barrier(0);
  }
}

// pack b (YS x XS f32) -> bpk[x][d] = bf16 pair (state 2d, state 2d+1), pre-scaled
__global__ __launch_bounds__(256) void pack_b(
    const float* __restrict__ b, unsigned* __restrict__ bpk)
{
  __shared__ float tileb[64][65];
  int x0 = blockIdx.x << 6;
  int lane = threadIdx.x & 63;
  int w = threadIdx.x >> 6;
  int xg = x0 + lane;
#pragma unroll
  for (int yy = 0; yy < 64; yy += 4) {
    int y = yy + w;
    tileb[y][lane] = (xg < XS) ? b[(size_t)y * XS + xg] * BSCALE : 0.f;
  }
  __syncthreads();
  int d = threadIdx.x & 31;           // dword slot = state pair (2d, 2d+1)
  int xo = threadIdx.x >> 5;          // 0..7
#pragma unroll
  for (int pass = 0; pass < 8; pass++) {
    int xl = pass * 8 + xo;
    int xcur = x0 + xl;
    if (xcur < XS)
      bpk[(size_t)xcur * 32 + d] = cvtpk(tileb[2 * d][xl], tileb[2 * d + 1][xl]);
  }
}

extern "C" void kernel_launch(void* const* d_in, const int* in_sizes, int n_in,
                              void* d_out, int out_size, void* d_ws, size_t ws_size,
                              hipStream_t stream)
{
  const int*   x  = (const int*)d_in[0];
  const float* A  = (const float*)d_in[1];
  const float* b  = (const float*)d_in[2];
  const float* pi = (const float*)d_in[3];
  float* out = (float*)d_out;

  const size_t bpk_bytes = (size_t)XS * 32 * sizeof(unsigned);  // 6.4 MB

  if (ws_size >= bpk_bytes) {
    unsigned* bpk = (unsigned*)d_ws;
    int tblocks = (XS + 63) / 64;
    pack_b<<<tblocks, 256, 0, stream>>>(b, bpk);
    hmm_fwd<true><<<NBLK, 256, 0, stream>>>(x, A, pi, b, bpk, out);
  } else {
    hmm_fwd<false><<<NBLK, 256, 0, stream>>>(x, A, pi, b, nullptr, out);
  }
}

// Round 13
// 73.075 us; speedup vs baseline: 1.2889x; 1.0389x over previous
//
#include <hip/hip_runtime.h>

#define TLEN 1000000
#define YS 64
#define XS 50000
#define CHUNK 64
#define WARM 8
#define SPAN (CHUNK + WARM)                    // 72 steps/wave
#define NWIN (CHUNK / 4)                       // 16 flush windows
#define NCHUNK (TLEN / CHUNK)                  // 15625
#define RPW 16                                 // chunks per wave (MFMA N dim)
#define NW ((NCHUNK + RPW - 1) / RPW)          // 977
#define WPB 4
#define NBLK ((NW + WPB - 1) / WPB)            // 245
#define BSCALE ((float)XS)                     // keeps bf16 e near 1

typedef float f32x4 __attribute__((ext_vector_type(4)));
typedef short bf16x8 __attribute__((ext_vector_type(8)));
typedef unsigned int u32x4 __attribute__((ext_vector_type(4)));

__device__ __forceinline__ unsigned cvtpk(float lo, float hi) {
  unsigned r;
  asm("v_cvt_pk_bf16_f32 %0, %1, %2" : "=v"(r) : "v"(lo), "v"(hi));
  return r;
}
__device__ __forceinline__ unsigned short f2bf_rne(float f) {
  unsigned u = __float_as_uint(f);
  unsigned r = (u + 0x7FFFu + ((u >> 16) & 1u)) >> 16;
  return (unsigned short)r;
}
__device__ __forceinline__ float bfu_lo(unsigned d) { return __uint_as_float(d << 16); }
__device__ __forceinline__ float bfu_hi(unsigned d) { return __uint_as_float(d & 0xffff0000u); }
__device__ __forceinline__ int clamp01(int t) {
  t = t < 0 ? 0 : t;
  return t > (TLEN - 1) ? (TLEN - 1) : t;
}

union bfu { u32x4 u; bf16x8 b; };

// Register-resident rho-relabeled MFMA recurrence (R8-proven numerics) +
// fenced LDS-staged NT-store output (R12-proven) + CHUNK=64/WARM=8
// (warm-up gather overhead 25%->12.5%) + 4-deep e-prefetch ring (R11-proven)
// to cover HBM gather latency at ~1 wave/SIMD occupancy.
template <bool USE_BT>
__global__ __launch_bounds__(256, 2) void hmm_fwd(
    const int* __restrict__ x, const float* __restrict__ A,
    const float* __restrict__ pi, const float* __restrict__ b,
    const unsigned* __restrict__ bpk, float* __restrict__ out)
{
  __shared__ __align__(16) float tile[WPB][64][64];   // 64KB: 4 steps x 16 chunks x 256B per wave
  const int wslot = threadIdx.x >> 6;
  const int wv = blockIdx.x * WPB + wslot;
  const int lane = threadIdx.x & 63;
  if (wv >= NW) return;
  const int g = lane >> 4, c15 = lane & 15;

  // static A-operand fragments: Af[nt][h][j] = T[sin][sout], bf16
  bf16x8 Af[4][2];
#pragma unroll
  for (int nt = 0; nt < 4; nt++) {
    int sout = 32 * (nt >> 1) + 8 * (c15 >> 2) + 4 * (nt & 1) + (c15 & 3);
#pragma unroll
    for (int h = 0; h < 2; h++) {
      bf16x8 v;
#pragma unroll
      for (int j = 0; j < 8; j++) {
        int sin = 32 * h + 8 * g + j;
        v[j] = (short)f2bf_rne(A[sin * YS + sout]);
      }
      Af[nt][h] = v;
    }
  }

  const int tj0 = (wv * RPW + c15) * CHUNK - WARM;
  const bool isw0 = (wv == 0);

  // carry B-frags: uniform start (warm-up forgets it; renormalized every step)
  u32x4 cb0, cb1;
  { unsigned one2 = 0x3f803f80u; cb0 = (u32x4){one2, one2, one2, one2}; cb1 = cb0; }

  // packed-e loader: L0 = states (8g..8g+7), L1 = states (32+8g..32+8g+7)
  auto eload = [&](int xt, u32x4& L0, u32x4& L1) {
    if (USE_BT) {
      const u32x4* p = (const u32x4*)(bpk + (size_t)(unsigned)xt * 32);
      L0 = p[g];
      L1 = p[4 + g];
    } else {
      unsigned t0[4], t1[4];
#pragma unroll
      for (int d = 0; d < 4; d++) {
        int s = 8 * g + 2 * d;
        t0[d] = cvtpk(b[(size_t)s * XS + xt] * BSCALE,
                      b[(size_t)(s + 1) * XS + xt] * BSCALE);
        int s2 = 32 + 8 * g + 2 * d;
        t1[d] = cvtpk(b[(size_t)s2 * XS + xt] * BSCALE,
                      b[(size_t)(s2 + 1) * XS + xt] * BSCALE);
      }
      L0 = (u32x4){t0[0], t0[1], t0[2], t0[3]};
      L1 = (u32x4){t1[0], t1[1], t1[2], t1[3]};
    }
  };

  // prefetch rings: e for steps 0..3 (4-deep); x values for steps 4..7
  u32x4 eL0[4], eL1[4];
  int xv[4];
#pragma unroll
  for (int u = 0; u < 4; u++) {
    eload(x[clamp01(tj0 + u)], eL0[u], eL1[u]);
    xv[u] = x[clamp01(tj0 + 4 + u)];
  }

  const f32x4 z4 = {0.f, 0.f, 0.f, 0.f};

  auto stepf = [&](int sabs, int u) {
    bfu ub0, ub1; ub0.u = cb0; ub1.u = cb1;
    bf16x8 bb0 = ub0.b, bb1 = ub1.b;

    f32x4 D0 = __builtin_amdgcn_mfma_f32_16x16x32_bf16(Af[0][0], bb0, z4, 0, 0, 0);
    f32x4 D1 = __builtin_amdgcn_mfma_f32_16x16x32_bf16(Af[1][0], bb0, z4, 0, 0, 0);
    f32x4 D2 = __builtin_amdgcn_mfma_f32_16x16x32_bf16(Af[2][0], bb0, z4, 0, 0, 0);
    f32x4 D3 = __builtin_amdgcn_mfma_f32_16x16x32_bf16(Af[3][0], bb0, z4, 0, 0, 0);
    D0 = __builtin_amdgcn_mfma_f32_16x16x32_bf16(Af[0][1], bb1, D0, 0, 0, 0);
    D1 = __builtin_amdgcn_mfma_f32_16x16x32_bf16(Af[1][1], bb1, D1, 0, 0, 0);
    D2 = __builtin_amdgcn_mfma_f32_16x16x32_bf16(Af[2][1], bb1, D2, 0, 0, 0);
    D3 = __builtin_amdgcn_mfma_f32_16x16x32_bf16(Af[3][1], bb1, D3, 0, 0, 0);

    // emission fold: D[nt][j] *= e[state(nt,g,j)]
    u32x4 L0 = eL0[u], L1 = eL1[u];
    D0[0] *= bfu_lo(L0[0]); D0[1] *= bfu_hi(L0[0]); D0[2] *= bfu_lo(L0[1]); D0[3] *= bfu_hi(L0[1]);
    D1[0] *= bfu_lo(L0[2]); D1[1] *= bfu_hi(L0[2]); D1[2] *= bfu_lo(L0[3]); D1[3] *= bfu_hi(L0[3]);
    D2[0] *= bfu_lo(L1[0]); D2[1] *= bfu_hi(L1[0]); D2[2] *= bfu_lo(L1[1]); D2[3] *= bfu_hi(L1[1]);
    D3[0] *= bfu_lo(L1[2]); D3[1] *= bfu_hi(L1[2]); D3[2] *= bfu_lo(L1[3]); D3[3] *= bfu_hi(L1[3]);

    // chunk-0 exact init injection at its t=0 (one step, wave 0, chunk col 0)
    if (isw0 && sabs == WARM && c15 == 0) {
      int x0v = x[0];
#pragma unroll
      for (int nt = 0; nt < 4; nt++) {
#pragma unroll
        for (int j = 0; j < 4; j++) {
          int s = 32 * (nt >> 1) + 8 * g + 4 * (nt & 1) + j;
          float ov = pi[s] * b[(size_t)s * XS + x0v] * BSCALE;
          if (nt == 0) D0[j] = ov;
          else if (nt == 1) D1[j] = ov;
          else if (nt == 2) D2[j] = ov;
          else D3[j] = ov;
        }
      }
    }

    // exact per-step renormalization (chunk-uniform scale; kills all drift)
    f32x4 vs = (D0 + D1) + (D2 + D3);
    float ssum = (vs.x + vs.y) + (vs.z + vs.w);
    ssum += __shfl_xor(ssum, 16);
    ssum += __shfl_xor(ssum, 32);
    float r0 = __builtin_amdgcn_rcpf(ssum);
    float rs = r0 * fmaf(-ssum, r0, 2.0f);
    f32x4 N0 = D0 * rs, N1 = D1 * rs, N2 = D2 * rs, N3 = D3 * rs;

    // carry pack (critical path): D/N regs are exactly the next B-frag states
    cb0 = (u32x4){cvtpk(N0[0], N0[1]), cvtpk(N0[2], N0[3]),
                  cvtpk(N1[0], N1[1]), cvtpk(N1[2], N1[3])};
    cb1 = (u32x4){cvtpk(N2[0], N2[1]), cvtpk(N2[2], N2[3]),
                  cvtpk(N3[0], N3[1]), cvtpk(N3[2], N3[3])};

    // off-chain: stage normalized row into the LDS out-tile (XOR swizzled)
    if (sabs >= WARM) {
      const int srel = (sabs - WARM) & 3;
      float* rowp = &tile[wslot][4 * c15 + srel][0];
      const int xk = (c15 & 7) << 2;
      *(f32x4*)&rowp[(8 * g)      ^ xk] = N0;   // states 8g+0..3
      *(f32x4*)&rowp[(8 * g + 4)  ^ xk] = N1;   // states 8g+4..7
      *(f32x4*)&rowp[(32 + 8 * g) ^ xk] = N2;   // states 32+8g+0..3
      *(f32x4*)&rowp[(36 + 8 * g) ^ xk] = N3;   // states 32+8g+4..7
    }

    // refill rings: e for step sabs+4, x for step sabs+8
    eload(xv[u], eL0[u], eL1[u]);
    xv[u] = x[clamp01(tj0 + sabs + 8)];
  };

  // warm-up (no staging): WARM=8 = 2 macro-iterations
  for (int s = 0; s < WARM; s += 4) {
    stepf(s + 0, 0);
    stepf(s + 1, 1);
    stepf(s + 2, 2);
    stepf(s + 3, 3);
  }

  // output phase: NWIN windows x 4 steps; flush 16x 1KB contiguous islands,
  // NON-TEMPORAL (write-once stream must not evict bpk from L2)
  for (int w = 0; w < NWIN; w++) {
    const int sb = WARM + 4 * w;
    stepf(sb + 0, 0);
    stepf(sb + 1, 1);
    stepf(sb + 2, 2);
    stepf(sb + 3, 3);

    __builtin_amdgcn_sched_barrier(0);
    asm volatile("" ::: "memory");   // staging writes complete before flush reads
#pragma unroll
    for (int c = 0; c < 16; c++) {
      int gc = wv * RPW + c;
      if (gc < NCHUNK) {
        f32x4 v = *(const f32x4*)&tile[wslot][4 * c + g][(c15 * 4) ^ ((c & 7) << 2)];
        __builtin_nontemporal_store(v,
            (f32x4*)(out + ((size_t)gc * CHUNK + 4 * w + g) * YS + c15 * 4));
      }
    }
    asm volatile("" ::: "memory");   // flush reads complete before next staging writes
    __builtin_amdgcn_sched_barrier(0);
  }
}

// pack b (YS x XS f32) -> bpk[x][d] = bf16 pair (state 2d, state 2d+1), pre-scaled
__global__ __launch_bounds__(256) void pack_b(
    const float* __restrict__ b, unsigned* __restrict__ bpk)
{
  __shared__ float tileb[64][65];
  int x0 = blockIdx.x << 6;
  int lane = threadIdx.x & 63;
  int w = threadIdx.x >> 6;
  int xg = x0 + lane;
#pragma unroll
  for (int yy = 0; yy < 64; yy += 4) {
    int y = yy + w;
    tileb[y][lane] = (xg < XS) ? b[(size_t)y * XS + xg] * BSCALE : 0.f;
  }
  __syncthreads();
  int d = threadIdx.x & 31;           // dword slot = state pair (2d, 2d+1)
  int xo = threadIdx.x >> 5;          // 0..7
#pragma unroll
  for (int pass = 0; pass < 8; pass++) {
    int xl = pass * 8 + xo;
    int xcur = x0 + xl;
    if (xcur < XS)
      bpk[(size_t)xcur * 32 + d] = cvtpk(tileb[2 * d][xl], tileb[2 * d + 1][xl]);
  }
}

extern "C" void kernel_launch(void* const* d_in, const int* in_sizes, int n_in,
                              void* d_out, int out_size, void* d_ws, size_t ws_size,
                              hipStream_t stream)
{
  const int*   x  = (const int*)d_in[0];
  const float* A  = (const float*)d_in[1];
  const float* b  = (const float*)d_in[2];
  const float* pi = (const float*)d_in[3];
  float* out = (float*)d_out;

  const size_t bpk_bytes = (size_t)XS * 32 * sizeof(unsigned);  // 6.4 MB

  if (ws_size >= bpk_bytes) {
    unsigned* bpk = (unsigned*)d_ws;
    int tblocks = (XS + 63) / 64;
    pack_b<<<tblocks, 256, 0, stream>>>(b, bpk);
    hmm_fwd<true><<<NBLK, 256, 0, stream>>>(x, A, pi, b, bpk, out);
  } else {
    hmm_fwd<false><<<NBLK, 256, 0, stream>>>(x, A, pi, b, nullptr, out);
  }
}